// Round 2
// baseline (23876.553 us; speedup 1.0000x reference)
//
#include <hip/hip_runtime.h>

// ---------------------------------------------------------------------------
// LayerNorm-LSTM (depth=2) + FC, MI355X. fp32 in/out, split-bf16 (hi/lo)
// 3-term MFMA GEMMs for ~fp32 accuracy at bf16-matrix-core speed.
// B=64, T=512, D=H=1024, 4H=4096, C=1024.
// ---------------------------------------------------------------------------

typedef __attribute__((ext_vector_type(8))) short short8;
typedef __attribute__((ext_vector_type(8))) __bf16 bf16x8;
typedef __attribute__((ext_vector_type(4))) float f32x4;
typedef __attribute__((ext_vector_type(4))) unsigned short us4;

#define B_ 64
#define T_ 512
#define D_ 1024
#define H_ 1024
#define FH_ 4096
#define CHUNK_ 16              // time steps per pre-projection chunk
#define RCH_ (B_ * CHUNK_)     // 1024 rows per chunk

static __device__ __forceinline__ unsigned short f2bf(float f) {
  unsigned int u = __builtin_bit_cast(unsigned int, f);
  u += 0x7FFFu + ((u >> 16) & 1u);   // round-to-nearest-even
  return (unsigned short)(u >> 16);
}
static __device__ __forceinline__ float bf2f(unsigned short u) {
  unsigned int x = ((unsigned int)u) << 16;
  return __builtin_bit_cast(float, x);
}

// ---------------- split-cast fp32 -> (hi, lo) bf16 ----------------
__global__ void cast_split_k(const float4* __restrict__ in,
                             us4* __restrict__ hi, us4* __restrict__ lo, int n4) {
  int i = blockIdx.x * 256 + threadIdx.x;
  if (i < n4) {
    float4 v = in[i];
    us4 h, l;
    h[0] = f2bf(v.x); l[0] = f2bf(v.x - bf2f(h[0]));
    h[1] = f2bf(v.y); l[1] = f2bf(v.y - bf2f(h[1]));
    h[2] = f2bf(v.z); l[2] = f2bf(v.z - bf2f(h[2]));
    h[3] = f2bf(v.w); l[3] = f2bf(v.w - bf2f(h[3]));
    hi[i] = h; lo[i] = l;
  }
}

// ------ transpose-split input [B][T][D] f32 -> [T][B][D] (hi, lo) bf16 -----
__global__ void transpose_split_k(const float4* __restrict__ x,
                                  us4* __restrict__ hi, us4* __restrict__ lo) {
  int i = blockIdx.x * 256 + threadIdx.x;   // over T*B*D/4 = 8388608
  int d4  = i & 255;          // D/4 = 256
  int rem = i >> 8;
  int b = rem & 63;
  int t = rem >> 6;
  float4 v = x[((size_t)(b * T_ + t) << 8) + d4];
  us4 h, l;
  h[0] = f2bf(v.x); l[0] = f2bf(v.x - bf2f(h[0]));
  h[1] = f2bf(v.y); l[1] = f2bf(v.y - bf2f(h[1]));
  h[2] = f2bf(v.z); l[2] = f2bf(v.z - bf2f(h[2]));
  h[3] = f2bf(v.w); l[3] = f2bf(v.w - bf2f(h[3]));
  size_t o = ((size_t)(t * B_ + b) << 8) + d4;
  hi[o] = h; lo[o] = l;
}

// ---------------- 3-term split-bf16 GEMM ----------------
// out[r,n] = (Ahi+Alo)[r,:]·(Whi+Wlo)[n,:] + bias[n]   (dropping lo·lo)
// A,W: [RxK]/[NxK] bf16 row-major. 128x128 tile, BK=32, 4 waves (64x64 each).
// FCMODE: row r = t*B+b, store out[b][t][n].
template <int FCMODE>
__global__ __launch_bounds__(256) void gemm3_k(
    const unsigned short* __restrict__ Ahi, const unsigned short* __restrict__ Alo,
    const unsigned short* __restrict__ Whi, const unsigned short* __restrict__ Wlo,
    const float* __restrict__ bias, float* __restrict__ out, int K, int N) {
  __shared__ unsigned short lAh[128 * 40];
  __shared__ unsigned short lAl[128 * 40];
  __shared__ unsigned short lWh[128 * 40];
  __shared__ unsigned short lWl[128 * 40];
  int tid = threadIdx.x;
  int l = tid & 63, w = tid >> 6;
  int r0 = blockIdx.y * 128, c0 = blockIdx.x * 128;
  int wr = (w >> 1) * 64, wc = (w & 1) * 64;
  int lr = l & 15, lk = (l >> 4) * 8;
  f32x4 acc[4][4] = {};

  int srow = tid >> 2;           // 0..63
  int scc  = (tid & 3) * 8;      // 0,8,16,24

  for (int kt = 0; kt < K; kt += 32) {
#pragma unroll
    for (int i = 0; i < 2; ++i) {
      int row = srow + i * 64;
      size_t aoff = (size_t)(r0 + row) * K + kt + scc;
      size_t woff = (size_t)(c0 + row) * K + kt + scc;
      *(short8*)&lAh[row * 40 + scc] = *(const short8*)(Ahi + aoff);
      *(short8*)&lAl[row * 40 + scc] = *(const short8*)(Alo + aoff);
      *(short8*)&lWh[row * 40 + scc] = *(const short8*)(Whi + woff);
      *(short8*)&lWl[row * 40 + scc] = *(const short8*)(Wlo + woff);
    }
    __syncthreads();
    bf16x8 ah[4], al[4], bh[4], bl[4];
#pragma unroll
    for (int mi = 0; mi < 4; ++mi) {
      ah[mi] = *(bf16x8*)&lAh[(wr + mi * 16 + lr) * 40 + lk];
      al[mi] = *(bf16x8*)&lAl[(wr + mi * 16 + lr) * 40 + lk];
    }
#pragma unroll
    for (int ni = 0; ni < 4; ++ni) {
      bh[ni] = *(bf16x8*)&lWh[(wc + ni * 16 + lr) * 40 + lk];
      bl[ni] = *(bf16x8*)&lWl[(wc + ni * 16 + lr) * 40 + lk];
    }
#pragma unroll
    for (int mi = 0; mi < 4; ++mi)
#pragma unroll
      for (int ni = 0; ni < 4; ++ni) {
        acc[mi][ni] = __builtin_amdgcn_mfma_f32_16x16x32_bf16(ah[mi], bh[ni], acc[mi][ni], 0, 0, 0);
        acc[mi][ni] = __builtin_amdgcn_mfma_f32_16x16x32_bf16(ah[mi], bl[ni], acc[mi][ni], 0, 0, 0);
        acc[mi][ni] = __builtin_amdgcn_mfma_f32_16x16x32_bf16(al[mi], bh[ni], acc[mi][ni], 0, 0, 0);
      }
    __syncthreads();
  }

#pragma unroll
  for (int mi = 0; mi < 4; ++mi)
#pragma unroll
    for (int ni = 0; ni < 4; ++ni)
#pragma unroll
      for (int reg = 0; reg < 4; ++reg) {
        int r = r0 + wr + mi * 16 + (l >> 4) * 4 + reg;
        int c = c0 + wc + ni * 16 + lr;
        float v = acc[mi][ni][reg] + bias[c];
        if (FCMODE) {
          int b = r & 63, t = r >> 6;
          out[((size_t)b * T_ + t) * (size_t)N + c] = v;
        } else {
          out[(size_t)r * N + c] = v;
        }
      }
}

// ---------------- recurrent hh GEMM (3-term split): partials ------------
// h [64 x 1024] hi/lo bf16, W [4096 x 1024] hi/lo bf16. Grid (128, 4):
// 32-col tiles x 4-way K-split. Wave = 2 row-frags x 1 col-frag, K=256.
__global__ __launch_bounds__(256) void hh_gemm3_k(
    const unsigned short* __restrict__ hHi, const unsigned short* __restrict__ hLo,
    const unsigned short* __restrict__ Whi, const unsigned short* __restrict__ Wlo,
    float* __restrict__ HPp) {
  int tid = threadIdx.x;
  int l = tid & 63, w = tid >> 6;
  int lr = l & 15, lk = (l >> 4) * 8;
  int n0 = blockIdx.x * 32 + (w & 1) * 16;
  int m0 = (w >> 1) * 32;
  int kbase = blockIdx.y * 256;
  f32x4 acc[2] = {};
#pragma unroll
  for (int kc = 0; kc < 8; ++kc) {
    int kk = kbase + kc * 32 + lk;
    bf16x8 vbh = __builtin_bit_cast(bf16x8, *(const short8*)(Whi + (size_t)(n0 + lr) * 1024 + kk));
    bf16x8 vbl = __builtin_bit_cast(bf16x8, *(const short8*)(Wlo + (size_t)(n0 + lr) * 1024 + kk));
    bf16x8 a0h = __builtin_bit_cast(bf16x8, *(const short8*)(hHi + (size_t)(m0 + lr) * 1024 + kk));
    bf16x8 a0l = __builtin_bit_cast(bf16x8, *(const short8*)(hLo + (size_t)(m0 + lr) * 1024 + kk));
    bf16x8 a1h = __builtin_bit_cast(bf16x8, *(const short8*)(hHi + (size_t)(m0 + 16 + lr) * 1024 + kk));
    bf16x8 a1l = __builtin_bit_cast(bf16x8, *(const short8*)(hLo + (size_t)(m0 + 16 + lr) * 1024 + kk));
    acc[0] = __builtin_amdgcn_mfma_f32_16x16x32_bf16(a0h, vbh, acc[0], 0, 0, 0);
    acc[0] = __builtin_amdgcn_mfma_f32_16x16x32_bf16(a0h, vbl, acc[0], 0, 0, 0);
    acc[0] = __builtin_amdgcn_mfma_f32_16x16x32_bf16(a0l, vbh, acc[0], 0, 0, 0);
    acc[1] = __builtin_amdgcn_mfma_f32_16x16x32_bf16(a1h, vbh, acc[1], 0, 0, 0);
    acc[1] = __builtin_amdgcn_mfma_f32_16x16x32_bf16(a1h, vbl, acc[1], 0, 0, 0);
    acc[1] = __builtin_amdgcn_mfma_f32_16x16x32_bf16(a1l, vbh, acc[1], 0, 0, 0);
  }
  float* outp = HPp + (size_t)blockIdx.y * 64 * FH_;
#pragma unroll
  for (int mi = 0; mi < 2; ++mi)
#pragma unroll
    for (int reg = 0; reg < 4; ++reg) {
      int row = m0 + mi * 16 + (l >> 4) * 4 + reg;
      int col = blockIdx.x * 32 + (w & 1) * 16 + lr;
      outp[(size_t)row * FH_ + col] = acc[mi][reg];
    }
}

// ---------------- pointwise: LNx2 + gates + cell update + cell-LN ----------
__device__ __forceinline__ void wave_red(float& v) {
#pragma unroll
  for (int o = 32; o; o >>= 1) v += __shfl_down(v, o);
}

__global__ __launch_bounds__(256) void pointwise_k(
    const float* __restrict__ Pt,    // [64][4096] (includes b_ih)
    const float* __restrict__ HPp,   // [4][64][4096]
    const float* __restrict__ bhh, const float* __restrict__ gih,
    const float* __restrict__ beih, const float* __restrict__ ghh,
    const float* __restrict__ behh, const float* __restrict__ gho,
    const float* __restrict__ beho,
    float* __restrict__ cst,
    unsigned short* __restrict__ hH, unsigned short* __restrict__ hL,
    unsigned short* __restrict__ YtH, unsigned short* __restrict__ YtL) {
  __shared__ float red[16];
  int r = blockIdx.x, j = threadIdx.x;
  int wv = j >> 6, ln = j & 63;
  const float* Pr = Pt + (size_t)r * FH_;
  const float* Hr = HPp + (size_t)r * FH_;
  const size_t PART = (size_t)64 * FH_;

  float ihp[16], hhp[16];
  float s1 = 0, q1 = 0, s2 = 0, q2 = 0;
#pragma unroll
  for (int s = 0; s < 16; ++s) {
    int n = j + 256 * s;
    float a = Pr[n];
    float b = Hr[n] + Hr[n + PART] + Hr[n + 2 * PART] + Hr[n + 3 * PART] + bhh[n];
    ihp[s] = a; hhp[s] = b;
    s1 += a; q1 += a * a; s2 += b; q2 += b * b;
  }
  wave_red(s1); wave_red(q1); wave_red(s2); wave_red(q2);
  if (ln == 0) { red[wv * 4] = s1; red[wv * 4 + 1] = q1; red[wv * 4 + 2] = s2; red[wv * 4 + 3] = q2; }
  __syncthreads();
  s1 = red[0] + red[4] + red[8] + red[12];
  q1 = red[1] + red[5] + red[9] + red[13];
  s2 = red[2] + red[6] + red[10] + red[14];
  q2 = red[3] + red[7] + red[11] + red[15];
  __syncthreads();

  const float inv4h = 1.0f / 4096.0f;
  float m1 = s1 * inv4h, m2 = s2 * inv4h;
  float i1 = rsqrtf(q1 * inv4h - m1 * m1 + 1e-5f);
  float i2 = rsqrtf(q2 * inv4h - m2 * m2 + 1e-5f);

  float pre[16];
#pragma unroll
  for (int s = 0; s < 16; ++s) {
    int n = j + 256 * s;
    pre[s] = gih[n] * (ihp[s] - m1) * i1 + beih[n] + ghh[n] * (hhp[s] - m2) * i2 + behh[n];
  }

  float cn[4], og[4];
  float s3 = 0, q3 = 0;
#pragma unroll
  for (int u = 0; u < 4; ++u) {
    int hidx = j + 256 * u;
    float iG = 1.0f / (1.0f + __expf(-pre[u]));
    float fG = 1.0f / (1.0f + __expf(-pre[u + 4]));
    float oG = 1.0f / (1.0f + __expf(-pre[u + 8]));
    float gG = tanhf(pre[u + 12]);
    float c = fG * cst[(size_t)r * H_ + hidx] + iG * gG;
    cst[(size_t)r * H_ + hidx] = c;
    cn[u] = c; og[u] = oG;
    s3 += c; q3 += c * c;
  }
  wave_red(s3); wave_red(q3);
  if (ln == 0) { red[wv * 4] = s3; red[wv * 4 + 1] = q3; }
  __syncthreads();
  s3 = red[0] + red[4] + red[8] + red[12];
  q3 = red[1] + red[5] + red[9] + red[13];

  const float invh = 1.0f / 1024.0f;
  float m3 = s3 * invh;
  float i3 = rsqrtf(q3 * invh - m3 * m3 + 1e-5f);
#pragma unroll
  for (int u = 0; u < 4; ++u) {
    int hidx = j + 256 * u;
    float hy = og[u] * tanhf((cn[u] - m3) * i3 * gho[hidx] + beho[hidx]);
    unsigned short hv = f2bf(hy);
    unsigned short lv = f2bf(hy - bf2f(hv));
    hH[(size_t)r * H_ + hidx] = hv;
    hL[(size_t)r * H_ + hidx] = lv;
    YtH[(size_t)r * H_ + hidx] = hv;
    YtL[(size_t)r * H_ + hidx] = lv;
  }
}

// ---------------------------------------------------------------------------
extern "C" void kernel_launch(void* const* d_in, const int* in_sizes, int n_in,
                              void* d_out, int out_size, void* d_ws, size_t ws_size,
                              hipStream_t stream) {
  const float* x    = (const float*)d_in[0];
  const float* w_ih = (const float*)d_in[1];
  const float* b_ih = (const float*)d_in[2];
  const float* w_hh = (const float*)d_in[3];
  const float* b_hh = (const float*)d_in[4];
  const float* g_ih = (const float*)d_in[5];
  const float* be_ih= (const float*)d_in[6];
  const float* g_hh = (const float*)d_in[7];
  const float* be_hh= (const float*)d_in[8];
  const float* g_ho = (const float*)d_in[9];
  const float* be_ho= (const float*)d_in[10];
  const float* fc_w = (const float*)d_in[11];
  const float* fc_b = (const float*)d_in[12];
  float* out = (float*)d_out;

  // workspace carve-up (~216.5 MB)
  char* wsb = (char*)d_ws;
  size_t off = 0;
  unsigned short* wihHi = (unsigned short*)(wsb + off); off += 16777216;   // 2*4096*1024*2
  unsigned short* wihLo = (unsigned short*)(wsb + off); off += 16777216;
  unsigned short* whhHi = (unsigned short*)(wsb + off); off += 16777216;
  unsigned short* whhLo = (unsigned short*)(wsb + off); off += 16777216;
  unsigned short* fcHi  = (unsigned short*)(wsb + off); off += 2097152;    // 1024*1024*2
  unsigned short* fcLo  = (unsigned short*)(wsb + off); off += 2097152;
  unsigned short* XYhi  = (unsigned short*)(wsb + off); off += 67108864;   // [T*B][1024] bf16
  unsigned short* XYlo  = (unsigned short*)(wsb + off); off += 67108864;
  float* P              = (float*)(wsb + off); off += (size_t)RCH_ * FH_ * 4;  // 16 MB
  float* HPp            = (float*)(wsb + off); off += (size_t)4 * 64 * FH_ * 4; // 4 MB
  unsigned short* hbfH  = (unsigned short*)(wsb + off); off += 131072;
  unsigned short* hbfL  = (unsigned short*)(wsb + off); off += 131072;
  float* cst            = (float*)(wsb + off); off += 262144;
  (void)ws_size; (void)in_sizes; (void)n_in; (void)out_size;

  // --- splits ---
  {
    int n4 = 2 * FH_ * D_ / 4;  // 2,097,152
    cast_split_k<<<(n4 + 255) / 256, 256, 0, stream>>>((const float4*)w_ih, (us4*)wihHi, (us4*)wihLo, n4);
    cast_split_k<<<(n4 + 255) / 256, 256, 0, stream>>>((const float4*)w_hh, (us4*)whhHi, (us4*)whhLo, n4);
    int nf = H_ * H_ / 4;       // 262,144
    cast_split_k<<<(nf + 255) / 256, 256, 0, stream>>>((const float4*)fc_w, (us4*)fcHi, (us4*)fcLo, nf);
    int nx = T_ * B_ * D_ / 4;  // 8,388,608
    transpose_split_k<<<nx / 256, 256, 0, stream>>>((const float4*)x, (us4*)XYhi, (us4*)XYlo);
  }

  // --- layers ---
  for (int l = 0; l < 2; ++l) {
    hipMemsetAsync(hbfH, 0, 131072, stream);
    hipMemsetAsync(hbfL, 0, 131072, stream);
    hipMemsetAsync(cst, 0, 262144, stream);
    const unsigned short* WihHi = wihHi + (size_t)l * FH_ * D_;
    const unsigned short* WihLo = wihLo + (size_t)l * FH_ * D_;
    const unsigned short* WhhHi = whhHi + (size_t)l * FH_ * H_;
    const unsigned short* WhhLo = whhLo + (size_t)l * FH_ * H_;
    const float* bih = b_ih + l * FH_;
    const float* bhh = b_hh + l * FH_;
    const float* gih = g_ih + l * FH_;
    const float* beih= be_ih + l * FH_;
    const float* ghh = g_hh + l * FH_;
    const float* behh= be_hh + l * FH_;
    const float* gho = g_ho + l * H_;
    const float* beho= be_ho + l * H_;

    for (int ch = 0; ch < T_ / CHUNK_; ++ch) {
      // ih-projection for this chunk: [1024 x 4096] = A_chunk @ Wih^T + bih
      gemm3_k<0><<<dim3(FH_ / 128, RCH_ / 128), 256, 0, stream>>>(
          XYhi + (size_t)ch * RCH_ * D_, XYlo + (size_t)ch * RCH_ * D_,
          WihHi, WihLo, bih, P, D_, FH_);
      for (int tl = 0; tl < CHUNK_; ++tl) {
        int t = ch * CHUNK_ + tl;
        hh_gemm3_k<<<dim3(128, 4), 256, 0, stream>>>(hbfH, hbfL, WhhHi, WhhLo, HPp);
        pointwise_k<<<B_, 256, 0, stream>>>(
            P + (size_t)tl * B_ * FH_, HPp, bhh, gih, beih, ghh, behh, gho, beho,
            cst, hbfH, hbfL,
            XYhi + (size_t)t * B_ * H_, XYlo + (size_t)t * B_ * H_);
      }
    }
  }

  // --- final FC: out[b][t][c] = Y1[t*B+b,:]·fc_w[c,:] + fc_b ---
  gemm3_k<1><<<dim3(H_ / 128, (T_ * B_) / 128), 256, 0, stream>>>(
      XYhi, XYlo, fcHi, fcLo, fc_b, out, H_, H_);
}